// Round 9
// baseline (326.748 us; speedup 1.0000x reference)
//
#include <hip/hip_runtime.h>
#include <hip/hip_fp16.h>

#define NN     256
#define NF     127
#define DIM    128
#define NH     8
#define DH     64
#define INNER  512
#define DEPTH  6
#define NB     512
#define ATTN_SCALE 0.125f
#define LN_EPS 1e-5f

// load 4 consecutive fp16 -> float4 (8-byte load)
__device__ __forceinline__ float4 ldh4(const __half* p){
  __half2 h0 = ((const __half2*)p)[0];
  __half2 h1 = ((const __half2*)p)[1];
  float2 a = __half22float2(h0), b = __half22float2(h1);
  return make_float4(a.x, a.y, b.x, b.y);
}

__device__ __forceinline__ float wred_sum(float v){
#pragma unroll
  for(int o=32;o;o>>=1) v += __shfl_xor(v,o);
  return v;
}
__device__ __forceinline__ float wred_max(float v){
#pragma unroll
  for(int o=32;o;o>>=1) v = fmaxf(v,__shfl_xor(v,o));
  return v;
}
// block = 512 threads (8 waves). sred must have >= 8 floats.
__device__ __forceinline__ float block_sum(float v, float* sred, int t){
  v = wred_sum(v);
  __syncthreads();
  if((t&63)==0) sred[t>>6]=v;
  __syncthreads();
  float s = 0.f;
#pragma unroll
  for(int w=0; w<8; w++) s += sred[w];
  return s;
}

// LayerNorm over DIM values: in (LDS) -> out (LDS). All 512 threads call.
__device__ __forceinline__ void dev_ln(const float* in, float* out,
                                       const float* g, const float* b,
                                       float* sred, int t){
  float v = (t<DIM)? in[t] : 0.f;
  float m = block_sum(v,sred,t) * (1.f/DIM);
  float d = (t<DIM)? (v-m) : 0.f;
  float var = block_sum(d*d,sred,t) * (1.f/DIM);
  float rs = rsqrtf(var + LN_EPS);
  if(t<DIM) out[t] = d*rs*g[t] + b[t];
  __syncthreads();
}

// Q/K/V for one row i from xs[DIM] (LDS). fp32 weights, fp32 math.
// q fp32 row-major; k fp16 transposed [o][j]; v fp16 row-major. be folded in.
// 8 cols/thread, paired float4 weight loads for in-flight bytes.
__device__ __forceinline__ void dev_qkv8(const float* xs, int i,
    const float* Wq, const float* bq, const float* Wkv, const float* bkv,
    const float* be, float* qg, __half* kT, __half* vg, float* redS, int t){
  // ---- q: 64 col-groups(8) x 8 row-groups(16) ----
  {
    const int cg8 = (t&63)*8, rg = t>>6;
    float4 a0 = make_float4(0.f,0.f,0.f,0.f);
    float4 a1 = make_float4(0.f,0.f,0.f,0.f);
#pragma unroll
    for(int f=rg*16; f<rg*16+16; f++){
      float x = xs[f];
      float4 w0 = *(const float4*)(Wq + f*INNER + cg8);
      float4 w1 = *(const float4*)(Wq + f*INNER + cg8 + 4);
      a0.x=fmaf(x,w0.x,a0.x); a0.y=fmaf(x,w0.y,a0.y);
      a0.z=fmaf(x,w0.z,a0.z); a0.w=fmaf(x,w0.w,a0.w);
      a1.x=fmaf(x,w1.x,a1.x); a1.y=fmaf(x,w1.y,a1.y);
      a1.z=fmaf(x,w1.z,a1.z); a1.w=fmaf(x,w1.w,a1.w);
    }
    *(float4*)(redS + rg*INNER + cg8)     = a0;
    *(float4*)(redS + rg*INNER + cg8 + 4) = a1;
  }
  __syncthreads();
  {
    float s = bq[t];
#pragma unroll
    for(int g=0; g<8; g++) s += redS[g*INNER + t];
    qg[i*INNER+t] = s;
  }
  __syncthreads();
  // ---- kv: 128 col-groups(8) x 4 row-groups(32) ----
  {
    const int cg8 = (t&127)*8, rq = t>>7;
    float4 a0 = make_float4(0.f,0.f,0.f,0.f);
    float4 a1 = make_float4(0.f,0.f,0.f,0.f);
#pragma unroll
    for(int f=rq*32; f<rq*32+32; f++){
      float x = xs[f];
      float4 w0 = *(const float4*)(Wkv + f*(2*INNER) + cg8);
      float4 w1 = *(const float4*)(Wkv + f*(2*INNER) + cg8 + 4);
      a0.x=fmaf(x,w0.x,a0.x); a0.y=fmaf(x,w0.y,a0.y);
      a0.z=fmaf(x,w0.z,a0.z); a0.w=fmaf(x,w0.w,a0.w);
      a1.x=fmaf(x,w1.x,a1.x); a1.y=fmaf(x,w1.y,a1.y);
      a1.z=fmaf(x,w1.z,a1.z); a1.w=fmaf(x,w1.w,a1.w);
    }
    *(float4*)(redS + rq*1024 + cg8)     = a0;
    *(float4*)(redS + rq*1024 + cg8 + 4) = a1;
  }
  __syncthreads();
#pragma unroll
  for(int cc=0; cc<2; cc++){
    int c = t + cc*512;
    float s = redS[c] + redS[1024+c] + redS[2048+c] + redS[3072+c] + bkv[c];
    if(c < INNER) kT[c*NN+i]          = __float2half(s + be[c]);
    else          vg[i*INNER+c-INNER] = __float2half(s + be[c-INNER]);
  }
  __syncthreads();
}

// ---- fused node-init + LN1 + QKV for layer 0 ----
__global__ __launch_bounds__(512,2) void k_qkv0(const float* atom_emb, const float* noise,
    float* nodes,
    const float* ln1_g, const float* ln1_b,
    const float* Wq, const float* bq, const float* Wkv, const float* bkv, const float* be,
    float* qg, __half* kT, __half* vg){
  __shared__ float nd[DIM], xs[DIM], sred[8], redS[4096];
  int t = threadIdx.x, i = blockIdx.x;
  if(t<DIM){
    float v = (t<NF)? atom_emb[i*NF+t] : noise[0];
    nd[t] = v;
    nodes[i*DIM+t] = v;
  }
  __syncthreads();
  dev_ln(nd, xs, ln1_g, ln1_b, sred, t);
  dev_qkv8(xs, i, Wq, bq, Wkv, bkv, be, qg, kT, vg, redS, t);
}

// ---- fused per-row layer (512 thr, 1 row/block; fp32 weights, fp16 kv) ----
__global__ __launch_bounds__(512,2) void k_layer(
    float* nodes, const float* qg, const __half* kT, const __half* vg,
    float* qg_n, __half* kT_n, __half* vg_n,
    const int* bonds, const float* coords,
    const float* We,
    const float* Wo, const float* bo, const float* Wg1,
    const float* ln2_g, const float* ln2_b,
    const float* W1, const float* b1, const float* W2, const float* b2,
    const float* Wg2,
    const float* ln1_g_n, const float* ln1_b_n,
    const float* Wq_n, const float* bq_n, const float* Wkv_n, const float* bkv_n,
    const float* be_n, int has_next)
{
  __shared__ float nd[DIM], xs[DIM], qs[INNER], ao[INNER], o128[DIM];
  __shared__ float eL[NN*3], aW[NH*NN], redS[4096], sred[8], qWe[NH*3];
  const int t = threadIdx.x, i = blockIdx.x;

  if(t<DIM) nd[t] = nodes[i*DIM+t];
  qs[t] = qg[i*INNER+t];
  eL[t] = 0.f;
  if(t<NN) eL[512+t] = 0.f;
  __syncthreads();

  // build edge row i from bond list (duplicate writes carry identical values)
  {
    int bi = bonds[2*t], bj = bonds[2*t+1];
    if(bi==i || bj==i){
      float dx = coords[3*bi+0] - coords[3*bj+0];
      float dy = coords[3*bi+1] - coords[3*bj+1];
      float dz = coords[3*bi+2] - coords[3*bj+2];
      if(bi==i){ eL[bj*3+0]=dx;  eL[bj*3+1]=dy;  eL[bj*3+2]=dz;  }
      if(bj==i){ eL[bi*3+0]=-dx; eL[bi*3+1]=-dy; eL[bi*3+2]=-dz; }
    }
  }
  __syncthreads();

  if(t < NH*3){               // qWe[h][c] = q_i[h-slice] . We[c, h-slice]
    int h = t/3, c = t%3;
    float acc = 0.f;
    for(int d=0; d<DH; d++) acc = fmaf(qs[h*DH+d], We[c*INNER + h*DH + d], acc);
    qWe[t] = acc;
  }
  __syncthreads();

  // ---- attention: wave w == head w. no block barriers ----
  {
    const int h = t>>6, l = t&63, j0 = 4*l;
    const __half* kTh = kT + (h*DH)*NN;
    float s0=0.f,s1=0.f,s2=0.f,s3=0.f;
#pragma unroll 8
    for(int o=0; o<DH; o++){
      float qv = qs[h*DH+o];
      float4 kk = ldh4(kTh + o*NN + j0);
      s0=fmaf(qv,kk.x,s0); s1=fmaf(qv,kk.y,s1); s2=fmaf(qv,kk.z,s2); s3=fmaf(qv,kk.w,s3);
    }
    float w0=qWe[h*3+0], w1=qWe[h*3+1], w2=qWe[h*3+2];
    s0 += w0*eL[(j0+0)*3+0] + w1*eL[(j0+0)*3+1] + w2*eL[(j0+0)*3+2];
    s1 += w0*eL[(j0+1)*3+0] + w1*eL[(j0+1)*3+1] + w2*eL[(j0+1)*3+2];
    s2 += w0*eL[(j0+2)*3+0] + w1*eL[(j0+2)*3+1] + w2*eL[(j0+2)*3+2];
    s3 += w0*eL[(j0+3)*3+0] + w1*eL[(j0+3)*3+1] + w2*eL[(j0+3)*3+2];
    s0*=ATTN_SCALE; s1*=ATTN_SCALE; s2*=ATTN_SCALE; s3*=ATTN_SCALE;
    float mx = wred_max(fmaxf(fmaxf(s0,s1),fmaxf(s2,s3)));
    float p0=expf(s0-mx), p1=expf(s1-mx), p2=expf(s2-mx), p3=expf(s3-mx);
    float inv = 1.f / wred_sum(p0+p1+p2+p3);
    float a0=p0*inv, a1=p1*inv, a2=p2*inv, a3=p3*inv;
    float* aw = aW + h*NN;
    *(float4*)(aw + j0) = make_float4(a0,a1,a2,a3);
    // sc_c = sum_j a_j * edges[i,j,c]
    float c0 = a0*eL[(j0+0)*3+0]+a1*eL[(j0+1)*3+0]+a2*eL[(j0+2)*3+0]+a3*eL[(j0+3)*3+0];
    float c1 = a0*eL[(j0+0)*3+1]+a1*eL[(j0+1)*3+1]+a2*eL[(j0+2)*3+1]+a3*eL[(j0+3)*3+1];
    float c2 = a0*eL[(j0+0)*3+2]+a1*eL[(j0+1)*3+2]+a2*eL[(j0+2)*3+2]+a3*eL[(j0+3)*3+2];
    c0 = wred_sum(c0); c1 = wred_sum(c1); c2 = wred_sum(c2);
    __builtin_amdgcn_wave_barrier();   // order aW write before aW reads (same wave)
    // PV: lane l -> 8 outputs dq..dq+7, j-range jg*32..+31; fold over jg (8 groups)
    const int dq = (l&7)*8, jg = l>>3;
    const __half* vb = vg + h*DH + dq;
    float4 accA = make_float4(0.f,0.f,0.f,0.f);
    float4 accB = make_float4(0.f,0.f,0.f,0.f);
#pragma unroll 8
    for(int jj=0; jj<32; jj++){
      int j = jg*32 + jj;
      float a = aw[j];
      float4 v0 = ldh4(vb + j*INNER);
      float4 v1 = ldh4(vb + j*INNER + 4);
      accA.x=fmaf(a,v0.x,accA.x); accA.y=fmaf(a,v0.y,accA.y);
      accA.z=fmaf(a,v0.z,accA.z); accA.w=fmaf(a,v0.w,accA.w);
      accB.x=fmaf(a,v1.x,accB.x); accB.y=fmaf(a,v1.y,accB.y);
      accB.z=fmaf(a,v1.z,accB.z); accB.w=fmaf(a,v1.w,accB.w);
    }
#pragma unroll
    for(int o=8;o<64;o<<=1){
      accA.x += __shfl_xor(accA.x,o); accA.y += __shfl_xor(accA.y,o);
      accA.z += __shfl_xor(accA.z,o); accA.w += __shfl_xor(accA.w,o);
      accB.x += __shfl_xor(accB.x,o); accB.y += __shfl_xor(accB.y,o);
      accB.z += __shfl_xor(accB.z,o); accB.w += __shfl_xor(accB.w,o);
    }
    if(l<8){
      float4 we00 = *(const float4*)(We + 0*INNER + h*DH + dq);
      float4 we01 = *(const float4*)(We + 0*INNER + h*DH + dq + 4);
      float4 we10 = *(const float4*)(We + 1*INNER + h*DH + dq);
      float4 we11 = *(const float4*)(We + 1*INNER + h*DH + dq + 4);
      float4 we20 = *(const float4*)(We + 2*INNER + h*DH + dq);
      float4 we21 = *(const float4*)(We + 2*INNER + h*DH + dq + 4);
      float4 oA, oB;
      oA.x = accA.x + c0*we00.x + c1*we10.x + c2*we20.x;
      oA.y = accA.y + c0*we00.y + c1*we10.y + c2*we20.y;
      oA.z = accA.z + c0*we00.z + c1*we10.z + c2*we20.z;
      oA.w = accA.w + c0*we00.w + c1*we10.w + c2*we20.w;
      oB.x = accB.x + c0*we01.x + c1*we11.x + c2*we21.x;
      oB.y = accB.y + c0*we01.y + c1*we11.y + c2*we21.y;
      oB.z = accB.z + c0*we01.z + c1*we11.z + c2*we21.z;
      oB.w = accB.w + c0*we01.w + c1*we11.w + c2*we21.w;
      *(float4*)(ao + h*DH + dq)     = oA;
      *(float4*)(ao + h*DH + dq + 4) = oB;
    }
  }
  __syncthreads();

  // ---- Wo + gate1 ---- (16 col-groups(8) x 32 row-groups(16))
  {
    const int cg8 = (t&15)*8, rg = t>>4;
    float4 a0 = make_float4(0.f,0.f,0.f,0.f);
    float4 a1 = make_float4(0.f,0.f,0.f,0.f);
#pragma unroll
    for(int r=rg*16; r<rg*16+16; r++){
      float a = ao[r];
      float4 w0 = *(const float4*)(Wo + r*DIM + cg8);
      float4 w1 = *(const float4*)(Wo + r*DIM + cg8 + 4);
      a0.x=fmaf(a,w0.x,a0.x); a0.y=fmaf(a,w0.y,a0.y);
      a0.z=fmaf(a,w0.z,a0.z); a0.w=fmaf(a,w0.w,a0.w);
      a1.x=fmaf(a,w1.x,a1.x); a1.y=fmaf(a,w1.y,a1.y);
      a1.z=fmaf(a,w1.z,a1.z); a1.w=fmaf(a,w1.w,a1.w);
    }
    *(float4*)(redS + rg*DIM + cg8)     = a0;
    *(float4*)(redS + rg*DIM + cg8 + 4) = a1;
    __syncthreads();
    if(t<DIM){
      float s = bo[t];
#pragma unroll
      for(int g=0; g<32; g++) s += redS[g*DIM+t];
      o128[t] = s;
    }
    __syncthreads();
    float gv = 0.f;
    if(t<DIM){
      float o = o128[t], r = nd[t];
      gv = o*Wg1[t] + r*Wg1[DIM+t] + (o-r)*Wg1[2*DIM+t];
    }
    float gs = block_sum(gv, sred, t);
    float gate = 1.f/(1.f + expf(-gs));
    if(t<DIM) nd[t] = o128[t]*gate + nd[t]*(1.f-gate);
    __syncthreads();
  }

  // ---- LN2 + FFN(gelu exact) + gate2 ----
  dev_ln(nd, xs, ln2_g, ln2_b, sred, t);
  {
    const int cg8 = (t&63)*8, rg = t>>6;
    float4 a0 = make_float4(0.f,0.f,0.f,0.f);
    float4 a1 = make_float4(0.f,0.f,0.f,0.f);
#pragma unroll
    for(int f=rg*16; f<rg*16+16; f++){
      float x = xs[f];
      float4 w0 = *(const float4*)(W1 + f*INNER + cg8);
      float4 w1 = *(const float4*)(W1 + f*INNER + cg8 + 4);
      a0.x=fmaf(x,w0.x,a0.x); a0.y=fmaf(x,w0.y,a0.y);
      a0.z=fmaf(x,w0.z,a0.z); a0.w=fmaf(x,w0.w,a0.w);
      a1.x=fmaf(x,w1.x,a1.x); a1.y=fmaf(x,w1.y,a1.y);
      a1.z=fmaf(x,w1.z,a1.z); a1.w=fmaf(x,w1.w,a1.w);
    }
    *(float4*)(redS + rg*INNER + cg8)     = a0;
    *(float4*)(redS + rg*INNER + cg8 + 4) = a1;
  }
  __syncthreads();
  {
    float a = b1[t];
#pragma unroll
    for(int g=0; g<8; g++) a += redS[g*INNER + t];
    qs[t] = 0.5f*a*(1.f + erff(a*0.70710678118654752440f));
  }
  __syncthreads();
  {
    const int cg8 = (t&15)*8, rg = t>>4;
    float4 a0 = make_float4(0.f,0.f,0.f,0.f);
    float4 a1 = make_float4(0.f,0.f,0.f,0.f);
#pragma unroll
    for(int m=rg*16; m<rg*16+16; m++){
      float a = qs[m];
      float4 w0 = *(const float4*)(W2 + m*DIM + cg8);
      float4 w1 = *(const float4*)(W2 + m*DIM + cg8 + 4);
      a0.x=fmaf(a,w0.x,a0.x); a0.y=fmaf(a,w0.y,a0.y);
      a0.z=fmaf(a,w0.z,a0.z); a0.w=fmaf(a,w0.w,a0.w);
      a1.x=fmaf(a,w1.x,a1.x); a1.y=fmaf(a,w1.y,a1.y);
      a1.z=fmaf(a,w1.z,a1.z); a1.w=fmaf(a,w1.w,a1.w);
    }
    *(float4*)(redS + rg*DIM + cg8)     = a0;
    *(float4*)(redS + rg*DIM + cg8 + 4) = a1;
    __syncthreads();
    if(t<DIM){
      float s = b2[t];
#pragma unroll
      for(int g=0; g<32; g++) s += redS[g*DIM+t];
      o128[t] = s;
    }
    __syncthreads();
    float gv = 0.f;
    if(t<DIM){
      float y = o128[t], r = nd[t];
      gv = y*Wg2[t] + r*Wg2[DIM+t] + (y-r)*Wg2[2*DIM+t];
    }
    float gs = block_sum(gv, sred, t);
    float gate = 1.f/(1.f + expf(-gs));
    if(t<DIM) nd[t] = o128[t]*gate + nd[t]*(1.f-gate);
    __syncthreads();
  }
  if(t<DIM) nodes[i*DIM+t] = nd[t];

  // ---- next layer's LN1+QKV (writes the OTHER q/k/v buffer: no race) ----
  if(has_next){
    dev_ln(nd, xs, ln1_g_n, ln1_b_n, sred, t);
    dev_qkv8(xs, i, Wq_n, bq_n, Wkv_n, bkv_n, be_n, qg_n, kT_n, vg_n, redS, t);
  }
}

__global__ __launch_bounds__(64) void k_energy(const float* nodes, const float* out_w,
                                               const float* out_b, float* out){
  int i = blockIdx.x, l = threadIdx.x;
  float a = fmaf(nodes[i*DIM+l], out_w[l], nodes[i*DIM+64+l]*out_w[64+l]);
  a = wred_sum(a);
  if(l==0) out[i] = a + out_b[0];
}

extern "C" void kernel_launch(void* const* d_in, const int* in_sizes, int n_in,
                              void* d_out, int out_size, void* d_ws, size_t ws_size,
                              hipStream_t stream){
  const float* coords   = (const float*)d_in[0];
  const int*   bonds    = (const int*  )d_in[1];
  const float* noise    = (const float*)d_in[2];
  const float* atom_emb = (const float*)d_in[3];
  const float* ln1_g = (const float*)d_in[4];
  const float* ln1_b = (const float*)d_in[5];
  const float* Wq    = (const float*)d_in[6];
  const float* bq    = (const float*)d_in[7];
  const float* Wkv   = (const float*)d_in[8];
  const float* bkv   = (const float*)d_in[9];
  const float* We    = (const float*)d_in[10];
  const float* be    = (const float*)d_in[11];
  const float* Wo    = (const float*)d_in[12];
  const float* bo    = (const float*)d_in[13];
  const float* Wg1   = (const float*)d_in[14];
  const float* ln2_g = (const float*)d_in[15];
  const float* ln2_b = (const float*)d_in[16];
  const float* W1    = (const float*)d_in[17];
  const float* b1    = (const float*)d_in[18];
  const float* W2    = (const float*)d_in[19];
  const float* b2    = (const float*)d_in[20];
  const float* Wg2   = (const float*)d_in[21];
  const float* out_w = (const float*)d_in[22];
  const float* out_b = (const float*)d_in[23];

  // workspace: fp32 nodes 32768 | q0,q1 131072 each; then fp16 k0,k1,v0,v1 131072 each
  float* ws_f = (float*)d_ws;
  float* nodes   = ws_f;
  float* qbuf[2] = { ws_f + 32768, ws_f + 163840 };
  __half* hb = (__half*)(ws_f + 294912);
  __half* kbuf[2] = { hb,          hb + 131072 };
  __half* vbuf[2] = { hb + 262144, hb + 393216 };

  k_qkv0<<<256, 512, 0, stream>>>(atom_emb, noise, nodes, ln1_g, ln1_b,
                                  Wq, bq, Wkv, bkv, be,
                                  qbuf[0], kbuf[0], vbuf[0]);
  for(int l=0; l<DEPTH; l++){
    int cur = l&1, nxt = cur^1;
    int has_next = (l < DEPTH-1);
    int ln = has_next ? l+1 : l;    // keep pointers valid when unused
    k_layer<<<256, 512, 0, stream>>>(
      nodes, qbuf[cur], kbuf[cur], vbuf[cur],
      qbuf[nxt], kbuf[nxt], vbuf[nxt],
      bonds, coords,
      We  + (size_t)l*3*INNER,
      Wo  + (size_t)l*INNER*DIM, bo + (size_t)l*DIM, Wg1 + (size_t)l*3*DIM,
      ln2_g + (size_t)l*DIM, ln2_b + (size_t)l*DIM,
      W1  + (size_t)l*DIM*4*DIM, b1 + (size_t)l*4*DIM,
      W2  + (size_t)l*4*DIM*DIM, b2 + (size_t)l*DIM, Wg2 + (size_t)l*3*DIM,
      ln1_g + (size_t)ln*DIM, ln1_b + (size_t)ln*DIM,
      Wq  + (size_t)ln*DIM*INNER, bq + (size_t)ln*INNER,
      Wkv + (size_t)ln*DIM*2*INNER, bkv + (size_t)ln*2*INNER,
      be  + (size_t)ln*INNER, has_next);
  }
  k_energy<<<256, 64, 0, stream>>>(nodes, out_w, out_b, (float*)d_out);
}